// Round 4
// baseline (500.967 us; speedup 1.0000x reference)
//
#include <hip/hip_runtime.h>
#include <stdint.h>

// Problem constants
#define DMODEL 1024
#define NHEAD  16
#define DK     64
#define BATCH  4
#define SEQ    2048
#define MTOK   (BATCH * SEQ)   // 8192 token rows

typedef short bf16x8 __attribute__((ext_vector_type(8)));
typedef float f32x4  __attribute__((ext_vector_type(4)));
typedef float f32x16 __attribute__((ext_vector_type(16)));
typedef unsigned short u16x4 __attribute__((ext_vector_type(4)));
typedef unsigned short u16x8 __attribute__((ext_vector_type(8)));

// fp32 -> bf16 (RNE)
static __device__ __forceinline__ unsigned short f2bf(float f) {
    union { float f; unsigned u; } v; v.f = f;
    unsigned r = v.u + 0x7fffu + ((v.u >> 16) & 1u);
    return (unsigned short)(r >> 16);
}

// raw v_exp_f32: computes 2^x
static __device__ __forceinline__ float exp2_fast(float x) {
    float r;
    asm("v_exp_f32 %0, %1" : "=v"(r) : "v"(x));
    return r;
}

// v_cvt_pk_bf16_f32: pack 2 f32 -> u32 of 2 bf16 (lo = first arg)
static __device__ __forceinline__ unsigned cvtpk_bf16(float lo, float hi) {
    unsigned r;
    asm("v_cvt_pk_bf16_f32 %0, %1, %2" : "=v"(r) : "v"(lo), "v"(hi));
    return r;
}

// v_permlane32_swap_b32: a.hi32lanes <-> b.lo32lanes (guide T12 arg order)
static __device__ __forceinline__ void plane32_swap(unsigned &a, unsigned &b) {
    asm volatile("v_permlane32_swap_b32 %0, %1" : "+v"(a), "+v"(b));
}

// async global->LDS, 16B per lane. LDS dest is wave-uniform base + lane*16.
static __device__ __forceinline__ void gload_lds16(const void* gsrc, void* lds) {
    __builtin_amdgcn_global_load_lds(
        (__attribute__((address_space(1))) unsigned int*)gsrc,
        (__attribute__((address_space(3))) unsigned int*)lds, 16, 0, 0);
}

static __device__ __forceinline__ f32x4 mfma16(bf16x8 a, bf16x8 b, f32x4 c) {
    return __builtin_amdgcn_mfma_f32_16x16x32_bf16(a, b, c, 0, 0, 0);
}
static __device__ __forceinline__ f32x16 mfma32(bf16x8 a, bf16x8 b, f32x16 c) {
    return __builtin_amdgcn_mfma_f32_32x32x16_bf16(a, b, c, 0, 0, 0);
}

// ---------------------------------------------------------------------------
// Convert 4 weights (4 x 1M f32) + q,k,v (3 x 8M f32) to bf16 in ws.
// Layout (shorts): [0,4M) W(q,k,v,o); [4M,12M) q; [12M,20M) k; [20M,28M) v.
// ---------------------------------------------------------------------------
__global__ __launch_bounds__(256) void cvt_all(
    const float* __restrict__ q, const float* __restrict__ k,
    const float* __restrict__ v,
    const float* __restrict__ Wq, const float* __restrict__ Wk,
    const float* __restrict__ Wv, const float* __restrict__ Wo,
    unsigned short* __restrict__ ws)
{
    size_t e = ((size_t)blockIdx.x * 256 + threadIdx.x) * 8;   // 8 f32 / thread
    const float* src;
    if (e < (size_t)(4u << 20)) {
        int a = (int)(e >> 20);
        src = (a == 0 ? Wq : a == 1 ? Wk : a == 2 ? Wv : Wo) + (e & ((1u << 20) - 1));
    } else {
        size_t r = e - (size_t)(4u << 20);
        int which = (int)(r >> 23);
        src = (which == 0 ? q : which == 1 ? k : v) + (r & ((1u << 23) - 1));
    }
    float4 v0 = *(const float4*)src;
    float4 v1 = *(const float4*)(src + 4);
    u16x8 o = { f2bf(v0.x), f2bf(v0.y), f2bf(v0.z), f2bf(v0.w),
                f2bf(v1.x), f2bf(v1.y), f2bf(v1.z), f2bf(v1.w) };
    *(u16x8*)(ws + e) = o;
}

// ---------------------------------------------------------------------------
// 128x128-tile GEMM, C = A @ W^T + bias. A, W bf16 via global_load_lds.
// MODE 1: C bf16 transposed Vt[b][col][s]  (V projection, fallback path)
// MODE 2: C fp32 [8192,1024]               (output projection)
// ---------------------------------------------------------------------------
template<int MODE>
__global__ __launch_bounds__(256) void gemm128(
    const unsigned short* __restrict__ A, const unsigned short* __restrict__ Bw,
    const float* __restrict__ bias, void* __restrict__ Cany)
{
    __shared__ __align__(16) unsigned short As[128][32];
    __shared__ __align__(16) unsigned short Bs[128][32];

    const int tid  = threadIdx.x;
    const int lane = tid & 63;
    const int w    = tid >> 6;
    const int wr   = (w >> 1) * 64;
    const int wc   = (w & 1) * 64;
    const int g    = lane >> 4;
    const int q4   = lane & 15;
    const int rowbase = blockIdx.x * 128;
    const int colbase = blockIdx.y * 128;

    f32x4 acc[4][4];
#pragma unroll
    for (int m = 0; m < 4; m++)
#pragma unroll
        for (int n = 0; n < 4; n++) {
            acc[m][n][0] = 0.f; acc[m][n][1] = 0.f;
            acc[m][n][2] = 0.f; acc[m][n][3] = 0.f;
        }

    for (int k0 = 0; k0 < 1024; k0 += 32) {
#pragma unroll
        for (int i = 0; i < 2; i++) {
            int sIdx = i * 256 + w * 64 + lane;
            gload_lds16(A + (size_t)(rowbase + (sIdx >> 2)) * 1024 + k0 + (sIdx & 3) * 8,
                        &As[0][0] + (size_t)(i * 256 + w * 64) * 8);
            gload_lds16(Bw + (size_t)(colbase + (sIdx >> 2)) * 1024 + k0 + (sIdx & 3) * 8,
                        &Bs[0][0] + (size_t)(i * 256 + w * 64) * 8);
        }
        __syncthreads();

        bf16x8 af[4], bfr[4];
#pragma unroll
        for (int m = 0; m < 4; m++) af[m]  = *(const bf16x8*)&As[wr + m * 16 + q4][g * 8];
#pragma unroll
        for (int n = 0; n < 4; n++) bfr[n] = *(const bf16x8*)&Bs[wc + n * 16 + q4][g * 8];
#pragma unroll
        for (int m = 0; m < 4; m++)
#pragma unroll
            for (int n = 0; n < 4; n++)
                acc[m][n] = mfma16(af[m], bfr[n], acc[m][n]);
        __syncthreads();
    }

#pragma unroll
    for (int n = 0; n < 4; n++) {
        int col = colbase + wc + n * 16 + q4;
        float bv = bias[col];
#pragma unroll
        for (int m = 0; m < 4; m++) {
            int row0 = rowbase + wr + m * 16 + g * 4;
            if (MODE == 1) {
                unsigned short* C = (unsigned short*)Cany;
                int b = row0 >> 11, s0 = row0 & 2047;
                u16x4 o = { f2bf(acc[m][n][0] + bv), f2bf(acc[m][n][1] + bv),
                            f2bf(acc[m][n][2] + bv), f2bf(acc[m][n][3] + bv) };
                *(u16x4*)(C + ((size_t)((b << 10) + col)) * 2048 + s0) = o;
            } else {
                float* C = (float*)Cany;
#pragma unroll
                for (int r = 0; r < 4; r++)
                    C[(size_t)(row0 + r) * 1024 + col] = acc[m][n][r] + bv;
            }
        }
    }
}

// ---------------------------------------------------------------------------
// Fused QKV projection: gridDim.z selects z=0(Q),1(K),2(V->Vt transposed).
// Same m97 inner loop; 3x blocks per dispatch => >=3 blocks/CU.
// ---------------------------------------------------------------------------
__global__ __launch_bounds__(256) void gemm_qkv(
    const unsigned short* __restrict__ wsbase,
    const float* __restrict__ bq, const float* __restrict__ bk,
    const float* __restrict__ bv,
    unsigned short* __restrict__ Qw, unsigned short* __restrict__ Kw,
    unsigned short* __restrict__ VtO)
{
    const size_t M1 = (size_t)1 << 20;
    const int z = blockIdx.z;
    const unsigned short* A  = wsbase + 4 * M1 + (size_t)z * 8 * M1;
    const unsigned short* Bw = wsbase + (size_t)z * M1;
    const float* bias = (z == 0) ? bq : (z == 1) ? bk : bv;

    __shared__ __align__(16) unsigned short As[128][32];
    __shared__ __align__(16) unsigned short Bs[128][32];

    const int tid  = threadIdx.x;
    const int lane = tid & 63;
    const int w    = tid >> 6;
    const int wr   = (w >> 1) * 64;
    const int wc   = (w & 1) * 64;
    const int g    = lane >> 4;
    const int q4   = lane & 15;
    const int rowbase = blockIdx.x * 128;
    const int colbase = blockIdx.y * 128;

    f32x4 acc[4][4];
#pragma unroll
    for (int m = 0; m < 4; m++)
#pragma unroll
        for (int n = 0; n < 4; n++) {
            acc[m][n][0] = 0.f; acc[m][n][1] = 0.f;
            acc[m][n][2] = 0.f; acc[m][n][3] = 0.f;
        }

    for (int k0 = 0; k0 < 1024; k0 += 32) {
#pragma unroll
        for (int i = 0; i < 2; i++) {
            int sIdx = i * 256 + w * 64 + lane;
            gload_lds16(A + (size_t)(rowbase + (sIdx >> 2)) * 1024 + k0 + (sIdx & 3) * 8,
                        &As[0][0] + (size_t)(i * 256 + w * 64) * 8);
            gload_lds16(Bw + (size_t)(colbase + (sIdx >> 2)) * 1024 + k0 + (sIdx & 3) * 8,
                        &Bs[0][0] + (size_t)(i * 256 + w * 64) * 8);
        }
        __syncthreads();

        bf16x8 af[4], bfr[4];
#pragma unroll
        for (int m = 0; m < 4; m++) af[m]  = *(const bf16x8*)&As[wr + m * 16 + q4][g * 8];
#pragma unroll
        for (int n = 0; n < 4; n++) bfr[n] = *(const bf16x8*)&Bs[wc + n * 16 + q4][g * 8];
#pragma unroll
        for (int m = 0; m < 4; m++)
#pragma unroll
            for (int n = 0; n < 4; n++)
                acc[m][n] = mfma16(af[m], bfr[n], acc[m][n]);
        __syncthreads();
    }

#pragma unroll
    for (int n = 0; n < 4; n++) {
        int col = colbase + wc + n * 16 + q4;
        float bv2 = bias[col];
#pragma unroll
        for (int m = 0; m < 4; m++) {
            int row0 = rowbase + wr + m * 16 + g * 4;
            if (z < 2) {
                unsigned short* C = (z == 0) ? Qw : Kw;
#pragma unroll
                for (int r = 0; r < 4; r++)
                    C[(size_t)(row0 + r) * 1024 + col] = f2bf(acc[m][n][r] + bv2);
            } else {
                int b = row0 >> 11, s0 = row0 & 2047;
                u16x4 o = { f2bf(acc[m][n][0] + bv2), f2bf(acc[m][n][1] + bv2),
                            f2bf(acc[m][n][2] + bv2), f2bf(acc[m][n][3] + bv2) };
                *(u16x4*)(VtO + ((size_t)((b << 10) + col)) * 2048 + s0) = o;
            }
        }
    }
}

// ---------------------------------------------------------------------------
// Causal flash attention v3 — swapped-operand 32x32 MFMA, zero LDS, zero
// barriers. One wave = 32 q-rows (one q-row per lane pair); each lane owns
// its row's softmax state. S^T = mfma32(K, Q^T); O^T = mfma32(V^T, P^T).
// P^T B-frags built in-register via cvt_pk_bf16 + permlane32_swap (T12).
// 4096 independent wave-tasks, heavy q-tiles dispatched first.
// ---------------------------------------------------------------------------
__global__ __launch_bounds__(256, 4) void attn_kernel(
    const unsigned short* __restrict__ Q, const unsigned short* __restrict__ K,
    const unsigned short* __restrict__ Vt, unsigned short* __restrict__ ctx)
{
    const int lane = threadIdx.x & 63;
    const int w    = threadIdx.x >> 6;
    const int l31  = lane & 31;
    const int hi8  = (lane >> 5) * 8;   // 0 or 8
    const int hi4  = (lane >> 5) * 4;   // 0 or 4

    const int task = blockIdx.x * 4 + w;           // 0..4095
    const int b  = task >> 10;
    const int rr = task & 1023;
    const int h  = rr & 15;
    const int qt = 63 - (rr >> 4);                 // heavy first
    const int qbase = qt * 32;

    // Q B-frags: lane holds Q[qbase+l31][d*16 + hi8 + j]
    const unsigned short* qp = Q + (size_t)(b * 2048 + qbase + l31) * 1024 + h * 64 + hi8;
    bf16x8 qf[4];
#pragma unroll
    for (int d = 0; d < 4; d++) qf[d] = *(const bf16x8*)(qp + d * 16);

    f32x16 O0, O1;
#pragma unroll
    for (int i = 0; i < 16; i++) { O0[i] = 0.f; O1[i] = 0.f; }
    float m = -1e30f, l = 0.f;

    const unsigned short* kp  = K  + (size_t)(b * 2048 + l31) * 1024 + h * 64 + hi8;
    const unsigned short* vp0 = Vt + (size_t)(b * 1024 + h * 64 + l31) * 2048 + hi8;
    const unsigned short* vp1 = vp0 + (size_t)32 * 2048;

    const float SCL = 0.1803368801111204f;         // 0.125 * log2(e)
    const int nt = qt + 1;

    for (int it = 0; it < nt; ++it) {
        // ---- loads: K-tile A-frags + V-tile A-frags (V lands during softmax)
        bf16x8 kf[4], vf[4];
#pragma unroll
        for (int d = 0; d < 4; d++) kf[d] = *(const bf16x8*)(kp + d * 16);
        vf[0] = *(const bf16x8*)(vp0);
        vf[1] = *(const bf16x8*)(vp0 + 16);
        vf[2] = *(const bf16x8*)(vp1);
        vf[3] = *(const bf16x8*)(vp1 + 16);
        kp += 32 * 1024; vp0 += 32; vp1 += 32;

        // ---- S^T = K · Q^T  (D: col=q=l31, row=key=(reg&3)+8*(reg>>2)+hi4)
        f32x16 st;
#pragma unroll
        for (int i = 0; i < 16; i++) st[i] = 0.f;
        st = mfma32(kf[0], qf[0], st);
        st = mfma32(kf[1], qf[1], st);
        st = mfma32(kf[2], qf[2], st);
        st = mfma32(kf[3], qf[3], st);

        // ---- scale (+ causal mask on the diagonal tile only) ----
        const bool diag = (it == qt);
#pragma unroll
        for (int i = 0; i < 16; i++) {
            float vv = st[i] * SCL;
            if (diag) {
                int key = (i & 3) + 8 * (i >> 2) + hi4;
                if (key > l31) vv = -3e8f;
            }
            st[i] = vv;
        }

        // ---- row max: in-register tree + one cross-half shfl ----
        float t8[8], t4[4];
#pragma unroll
        for (int i = 0; i < 8; i++) t8[i] = fmaxf(st[i], st[i + 8]);
#pragma unroll
        for (int i = 0; i < 4; i++) t4[i] = fmaxf(t8[i], t8[i + 4]);
        float pm = fmaxf(fmaxf(t4[0], t4[1]), fmaxf(t4[2], t4[3]));
        pm = fmaxf(pm, __shfl_xor(pm, 32));

        // ---- defer-max (T13): rescale only when max moved > 8 nats ----
        if (__any(pm > m + 11.54f)) {
            float mn  = fmaxf(m, pm);
            float fac = exp2_fast(m - mn);
            m = mn; l *= fac;
#pragma unroll
            for (int i = 0; i < 16; i++) { O0[i] *= fac; O1[i] *= fac; }
        }

        // ---- P = exp2(S' - m); row sum ----
#pragma unroll
        for (int i = 0; i < 16; i++) st[i] = exp2_fast(st[i] - m);
        float s8[8], s4[4];
#pragma unroll
        for (int i = 0; i < 8; i++) s8[i] = st[i] + st[i + 8];
#pragma unroll
        for (int i = 0; i < 4; i++) s4[i] = s8[i] + s8[i + 4];
        float sm = (s4[0] + s4[1]) + (s4[2] + s4[3]);
        sm += __shfl_xor(sm, 32);
        l += sm;

        // ---- pack P -> P^T B-frags (8 cvt_pk + 4 permlane32_swap) ----
        union { unsigned u[4]; bf16x8 v; } pb0, pb1;
        {
            unsigned xA = cvtpk_bf16(st[0], st[1]);
            unsigned yC = cvtpk_bf16(st[4], st[5]);
            plane32_swap(xA, yC);
            unsigned xB = cvtpk_bf16(st[2], st[3]);
            unsigned yD = cvtpk_bf16(st[6], st[7]);
            plane32_swap(xB, yD);
            pb0.u[0] = xA; pb0.u[1] = xB; pb0.u[2] = yC; pb0.u[3] = yD;
        }
        {
            unsigned xA = cvtpk_bf16(st[8],  st[9]);
            unsigned yC = cvtpk_bf16(st[12], st[13]);
            plane32_swap(xA, yC);
            unsigned xB = cvtpk_bf16(st[10], st[11]);
            unsigned yD = cvtpk_bf16(st[14], st[15]);
            plane32_swap(xB, yD);
            pb1.u[0] = xA; pb1.u[1] = xB; pb1.u[2] = yC; pb1.u[3] = yD;
        }

        // ---- O^T += V^T · P^T ----
        O0 = mfma32(vf[0], pb0.v, O0);
        O0 = mfma32(vf[1], pb1.v, O0);
        O1 = mfma32(vf[2], pb0.v, O1);
        O1 = mfma32(vf[3], pb1.v, O1);
    }

    // ---- normalize, write ctx[b*2048+q][h*64+dk] ----
    const float rl = 1.0f / l;
    unsigned short* cp = ctx + (size_t)(b * 2048 + qbase + l31) * 1024 + h * 64;
#pragma unroll
    for (int grp = 0; grp < 4; grp++) {
        u16x4 o0 = { f2bf(O0[grp * 4 + 0] * rl), f2bf(O0[grp * 4 + 1] * rl),
                     f2bf(O0[grp * 4 + 2] * rl), f2bf(O0[grp * 4 + 3] * rl) };
        u16x4 o1 = { f2bf(O1[grp * 4 + 0] * rl), f2bf(O1[grp * 4 + 1] * rl),
                     f2bf(O1[grp * 4 + 2] * rl), f2bf(O1[grp * 4 + 3] * rl) };
        *(u16x4*)(cp + grp * 8 + hi4)      = o0;
        *(u16x4*)(cp + 32 + grp * 8 + hi4) = o1;
    }
}

// ---------------------------------------------------------------------------
extern "C" void kernel_launch(void* const* d_in, const int* in_sizes, int n_in,
                              void* d_out, int out_size, void* d_ws, size_t ws_size,
                              hipStream_t stream)
{
    const float* q  = (const float*)d_in[0];
    const float* k  = (const float*)d_in[1];
    const float* v  = (const float*)d_in[2];
    // d_in[3] = causal mask (tril) — handled analytically
    const float* Wq = (const float*)d_in[4];
    const float* bq = (const float*)d_in[5];
    const float* Wk = (const float*)d_in[6];
    const float* bk = (const float*)d_in[7];
    const float* Wv = (const float*)d_in[8];
    const float* bv = (const float*)d_in[9];
    const float* Wo = (const float*)d_in[10];
    const float* bo = (const float*)d_in[11];

    const size_t M1 = (size_t)1 << 20;
    unsigned short* ws   = (unsigned short*)d_ws;
    unsigned short* wo_b = ws + 3 * M1;
    unsigned short* vb16 = ws + 20 * M1;       // bf16 v input
    unsigned short* Qw   = ws + 28 * M1;       // [8192,1024] bf16
    unsigned short* Kw   = ws + 36 * M1;       // [8192,1024] bf16

    const bool big = ws_size >= (size_t)52 * M1 * 2;   // 104 MiB available?
    unsigned short* Vt = big ? (ws + 44 * M1)          // non-aliasing: full 3-way fuse
                             : (ws + 4 * M1);          // fallback: alias q-bf16 (dead)
    unsigned short* Cx = big ? (ws + 4 * M1)           // attn out (aliases dead q-bf16)
                             : (ws + 12 * M1);         //          (aliases dead k-bf16)

    cvt_all<<<14336, 256, 0, stream>>>(q, k, v, Wq, Wk, Wv, Wo, ws);

    if (big) {
        gemm_qkv<<<dim3(64, 8, 3), 256, 0, stream>>>(ws, bq, bk, bv, Qw, Kw, Vt);
    } else {
        gemm_qkv<<<dim3(64, 8, 2), 256, 0, stream>>>(ws, bq, bk, bv, Qw, Kw, Vt);
        gemm128<1><<<dim3(64, 8), 256, 0, stream>>>(vb16, ws + 2 * M1, bv, Vt);
    }

    attn_kernel<<<1024, 256, 0, stream>>>(Qw, Kw, Vt, Cx);

    gemm128<2><<<dim3(64, 8), 256, 0, stream>>>(Cx, wo_b, bo, d_out);
}

// Round 6
// 364.135 us; speedup vs baseline: 1.3758x; 1.3758x over previous
//
#include <hip/hip_runtime.h>
#include <stdint.h>

// Problem constants
#define DMODEL 1024
#define NHEAD  16
#define DK     64
#define BATCH  4
#define SEQ    2048
#define MTOK   (BATCH * SEQ)   // 8192 token rows

typedef short bf16x8 __attribute__((ext_vector_type(8)));
typedef float f32x4  __attribute__((ext_vector_type(4)));
typedef float f32x16 __attribute__((ext_vector_type(16)));
typedef unsigned short u16x4 __attribute__((ext_vector_type(4)));
typedef unsigned short u16x8 __attribute__((ext_vector_type(8)));

// fp32 -> bf16 (RNE)
static __device__ __forceinline__ unsigned short f2bf(float f) {
    union { float f; unsigned u; } v; v.f = f;
    unsigned r = v.u + 0x7fffu + ((v.u >> 16) & 1u);
    return (unsigned short)(r >> 16);
}

// raw v_exp_f32: computes 2^x
static __device__ __forceinline__ float exp2_fast(float x) {
    float r;
    asm("v_exp_f32 %0, %1" : "=v"(r) : "v"(x));
    return r;
}

// v_cvt_pk_bf16_f32: pack 2 f32 -> u32 of 2 bf16 (lo = first arg)
static __device__ __forceinline__ unsigned cvtpk_bf16(float lo, float hi) {
    unsigned r;
    asm("v_cvt_pk_bf16_f32 %0, %1, %2" : "=v"(r) : "v"(lo), "v"(hi));
    return r;
}

// v_permlane32_swap_b32: a.hi32lanes <-> b.lo32lanes
static __device__ __forceinline__ void plane32_swap(unsigned &a, unsigned &b) {
    asm volatile("v_permlane32_swap_b32 %0, %1" : "+v"(a), "+v"(b));
}

// async global->LDS, 16B per lane. LDS dest is wave-uniform base + lane*16.
static __device__ __forceinline__ void gload_lds16(const void* gsrc, void* lds) {
    __builtin_amdgcn_global_load_lds(
        (__attribute__((address_space(1))) unsigned int*)gsrc,
        (__attribute__((address_space(3))) unsigned int*)lds, 16, 0, 0);
}

static __device__ __forceinline__ f32x4 mfma16(bf16x8 a, bf16x8 b, f32x4 c) {
    return __builtin_amdgcn_mfma_f32_16x16x32_bf16(a, b, c, 0, 0, 0);
}
static __device__ __forceinline__ f32x16 mfma32(bf16x8 a, bf16x8 b, f32x16 c) {
    return __builtin_amdgcn_mfma_f32_32x32x16_bf16(a, b, c, 0, 0, 0);
}

// ---------------------------------------------------------------------------
// Convert 4 weights (4 x 1M f32) + q,k,v (3 x 8M f32) to bf16 in ws.
// Layout (shorts): [0,4M) W(q,k,v,o); [4M,12M) q; [12M,20M) k; [20M,28M) v.
// ---------------------------------------------------------------------------
__global__ __launch_bounds__(256) void cvt_all(
    const float* __restrict__ q, const float* __restrict__ k,
    const float* __restrict__ v,
    const float* __restrict__ Wq, const float* __restrict__ Wk,
    const float* __restrict__ Wv, const float* __restrict__ Wo,
    unsigned short* __restrict__ ws)
{
    size_t e = ((size_t)blockIdx.x * 256 + threadIdx.x) * 8;   // 8 f32 / thread
    const float* src;
    if (e < (size_t)(4u << 20)) {
        int a = (int)(e >> 20);
        src = (a == 0 ? Wq : a == 1 ? Wk : a == 2 ? Wv : Wo) + (e & ((1u << 20) - 1));
    } else {
        size_t r = e - (size_t)(4u << 20);
        int which = (int)(r >> 23);
        src = (which == 0 ? q : which == 1 ? k : v) + (r & ((1u << 23) - 1));
    }
    float4 v0 = *(const float4*)src;
    float4 v1 = *(const float4*)(src + 4);
    u16x8 o = { f2bf(v0.x), f2bf(v0.y), f2bf(v0.z), f2bf(v0.w),
                f2bf(v1.x), f2bf(v1.y), f2bf(v1.z), f2bf(v1.w) };
    *(u16x8*)(ws + e) = o;
}

// ---------------------------------------------------------------------------
// 128x128-tile GEMM, C = A @ W^T + bias. A, W bf16 via global_load_lds.
// MODE 1: C bf16 transposed Vt[b][col][s]  (V projection, fallback path)
// MODE 2: C fp32 [8192,1024]               (output projection)
// ---------------------------------------------------------------------------
template<int MODE>
__global__ __launch_bounds__(256) void gemm128(
    const unsigned short* __restrict__ A, const unsigned short* __restrict__ Bw,
    const float* __restrict__ bias, void* __restrict__ Cany)
{
    __shared__ __align__(16) unsigned short As[128][32];
    __shared__ __align__(16) unsigned short Bs[128][32];

    const int tid  = threadIdx.x;
    const int lane = tid & 63;
    const int w    = tid >> 6;
    const int wr   = (w >> 1) * 64;
    const int wc   = (w & 1) * 64;
    const int g    = lane >> 4;
    const int q4   = lane & 15;
    const int rowbase = blockIdx.x * 128;
    const int colbase = blockIdx.y * 128;

    f32x4 acc[4][4];
#pragma unroll
    for (int m = 0; m < 4; m++)
#pragma unroll
        for (int n = 0; n < 4; n++) {
            acc[m][n][0] = 0.f; acc[m][n][1] = 0.f;
            acc[m][n][2] = 0.f; acc[m][n][3] = 0.f;
        }

    for (int k0 = 0; k0 < 1024; k0 += 32) {
#pragma unroll
        for (int i = 0; i < 2; i++) {
            int sIdx = i * 256 + w * 64 + lane;
            gload_lds16(A + (size_t)(rowbase + (sIdx >> 2)) * 1024 + k0 + (sIdx & 3) * 8,
                        &As[0][0] + (size_t)(i * 256 + w * 64) * 8);
            gload_lds16(Bw + (size_t)(colbase + (sIdx >> 2)) * 1024 + k0 + (sIdx & 3) * 8,
                        &Bs[0][0] + (size_t)(i * 256 + w * 64) * 8);
        }
        __syncthreads();

        bf16x8 af[4], bfr[4];
#pragma unroll
        for (int m = 0; m < 4; m++) af[m]  = *(const bf16x8*)&As[wr + m * 16 + q4][g * 8];
#pragma unroll
        for (int n = 0; n < 4; n++) bfr[n] = *(const bf16x8*)&Bs[wc + n * 16 + q4][g * 8];
#pragma unroll
        for (int m = 0; m < 4; m++)
#pragma unroll
            for (int n = 0; n < 4; n++)
                acc[m][n] = mfma16(af[m], bfr[n], acc[m][n]);
        __syncthreads();
    }

#pragma unroll
    for (int n = 0; n < 4; n++) {
        int col = colbase + wc + n * 16 + q4;
        float bv = bias[col];
#pragma unroll
        for (int m = 0; m < 4; m++) {
            int row0 = rowbase + wr + m * 16 + g * 4;
            if (MODE == 1) {
                unsigned short* C = (unsigned short*)Cany;
                int b = row0 >> 11, s0 = row0 & 2047;
                u16x4 o = { f2bf(acc[m][n][0] + bv), f2bf(acc[m][n][1] + bv),
                            f2bf(acc[m][n][2] + bv), f2bf(acc[m][n][3] + bv) };
                *(u16x4*)(C + ((size_t)((b << 10) + col)) * 2048 + s0) = o;
            } else {
                float* C = (float*)Cany;
#pragma unroll
                for (int r = 0; r < 4; r++)
                    C[(size_t)(row0 + r) * 1024 + col] = acc[m][n][r] + bv;
            }
        }
    }
}

// ---------------------------------------------------------------------------
// Fused QKV projection: gridDim.z selects z=0(Q),1(K),2(V->Vt transposed).
// ---------------------------------------------------------------------------
__global__ __launch_bounds__(256) void gemm_qkv(
    const unsigned short* __restrict__ wsbase,
    const float* __restrict__ bq, const float* __restrict__ bk,
    const float* __restrict__ bv,
    unsigned short* __restrict__ Qw, unsigned short* __restrict__ Kw,
    unsigned short* __restrict__ VtO)
{
    const size_t M1 = (size_t)1 << 20;
    const int z = blockIdx.z;
    const unsigned short* A  = wsbase + 4 * M1 + (size_t)z * 8 * M1;
    const unsigned short* Bw = wsbase + (size_t)z * M1;
    const float* bias = (z == 0) ? bq : (z == 1) ? bk : bv;

    __shared__ __align__(16) unsigned short As[128][32];
    __shared__ __align__(16) unsigned short Bs[128][32];

    const int tid  = threadIdx.x;
    const int lane = tid & 63;
    const int w    = tid >> 6;
    const int wr   = (w >> 1) * 64;
    const int wc   = (w & 1) * 64;
    const int g    = lane >> 4;
    const int q4   = lane & 15;
    const int rowbase = blockIdx.x * 128;
    const int colbase = blockIdx.y * 128;

    f32x4 acc[4][4];
#pragma unroll
    for (int m = 0; m < 4; m++)
#pragma unroll
        for (int n = 0; n < 4; n++) {
            acc[m][n][0] = 0.f; acc[m][n][1] = 0.f;
            acc[m][n][2] = 0.f; acc[m][n][3] = 0.f;
        }

    for (int k0 = 0; k0 < 1024; k0 += 32) {
#pragma unroll
        for (int i = 0; i < 2; i++) {
            int sIdx = i * 256 + w * 64 + lane;
            gload_lds16(A + (size_t)(rowbase + (sIdx >> 2)) * 1024 + k0 + (sIdx & 3) * 8,
                        &As[0][0] + (size_t)(i * 256 + w * 64) * 8);
            gload_lds16(Bw + (size_t)(colbase + (sIdx >> 2)) * 1024 + k0 + (sIdx & 3) * 8,
                        &Bs[0][0] + (size_t)(i * 256 + w * 64) * 8);
        }
        __syncthreads();

        bf16x8 af[4], bfr[4];
#pragma unroll
        for (int m = 0; m < 4; m++) af[m]  = *(const bf16x8*)&As[wr + m * 16 + q4][g * 8];
#pragma unroll
        for (int n = 0; n < 4; n++) bfr[n] = *(const bf16x8*)&Bs[wc + n * 16 + q4][g * 8];
#pragma unroll
        for (int m = 0; m < 4; m++)
#pragma unroll
            for (int n = 0; n < 4; n++)
                acc[m][n] = mfma16(af[m], bfr[n], acc[m][n]);
        __syncthreads();
    }

#pragma unroll
    for (int n = 0; n < 4; n++) {
        int col = colbase + wc + n * 16 + q4;
        float bv2 = bias[col];
#pragma unroll
        for (int m = 0; m < 4; m++) {
            int row0 = rowbase + wr + m * 16 + g * 4;
            if (z < 2) {
                unsigned short* C = (z == 0) ? Qw : Kw;
#pragma unroll
                for (int r = 0; r < 4; r++)
                    C[(size_t)(row0 + r) * 1024 + col] = f2bf(acc[m][n][r] + bv2);
            } else {
                int b = row0 >> 11, s0 = row0 & 2047;
                u16x4 o = { f2bf(acc[m][n][0] + bv2), f2bf(acc[m][n][1] + bv2),
                            f2bf(acc[m][n][2] + bv2), f2bf(acc[m][n][3] + bv2) };
                *(u16x4*)(VtO + ((size_t)((b << 10) + col)) * 2048 + s0) = o;
            }
        }
    }
}

// ---------------------------------------------------------------------------
// Causal flash attention v4 — swapped-operand 32x32 MFMA math (round-4
// verified) + coalesced double-buffered LDS staging (round-3 verified).
// Block = (b, h, 128-row q-tile), 4 waves x 32 q-rows. KVBLK=64.
// K tile [64 key][64 d] and V^T tile [64 d][64 key] in LDS, XOR-swizzled
// (linear dest + pre-swizzled source, ERRATA#21). Softmax per q-row held
// by one lane pair; P packed in-register via cvt_pk + permlane32_swap.
// ---------------------------------------------------------------------------
__global__ __launch_bounds__(256, 3) void attn_kernel(
    const unsigned short* __restrict__ Q, const unsigned short* __restrict__ K,
    const unsigned short* __restrict__ Vt, unsigned short* __restrict__ ctx)
{
    __shared__ __align__(16) unsigned char KsB[2][8192];   // [64 key][64 d] swz
    __shared__ __align__(16) unsigned char VsB[2][8192];   // [64 d][64 key] swz

    const int tid  = threadIdx.x;
    const int lane = tid & 63;
    const int w    = tid >> 6;
    const int l31  = lane & 31;
    const int hi8  = (lane >> 5) * 8;    // short offset of k-halves
    const int hi4  = (lane >> 5) * 4;    // reg-row offset
    const int hib  = hi8 * 2;            // byte offset
    const int swz  = (l31 & 7) << 4;     // row-XOR swizzle for LDS reads

    const int bid = blockIdx.x;          // 1024 = 4b * 16h * 16qt
    const int qt  = 15 - (bid & 15);     // heavy q-tiles first
    const int h   = (bid >> 4) & 15;
    const int b   = bid >> 8;
    const int qwave = qt * 128 + w * 32;
    const int qrow  = qwave + l31;       // this lane's q row (both halves)

    // Q B-frags: B[k = ks*16 + hi8 + j][col = l31]
    const unsigned short* qp = Q + (size_t)(b * 2048 + qrow) * 1024 + h * 64 + hi8;
    bf16x8 qf[4];
#pragma unroll
    for (int ks = 0; ks < 4; ks++) qf[ks] = *(const bf16x8*)(qp + ks * 16);

    f32x16 O0, O1;
#pragma unroll
    for (int i = 0; i < 16; i++) { O0[i] = 0.f; O1[i] = 0.f; }
    float m = -1e30f, l = 0.f;

    const float SCL = 0.1803368801111204f;   // 0.125 * log2(e)
    const int nt = 2 * (qt + 1);             // 64-key tiles

    // stage tile t (keys t*64..t*64+63) into buffer bsel
    auto STAGE = [&](int t, int bsel) {
#pragma unroll
        for (int i = 0; i < 2; i++) {
            int sIdx = i * 256 + w * 64 + lane;              // 0..511
            int rr   = sIdx >> 3;                            // row 0..63
            int cb   = ((sIdx & 7) * 16) ^ ((rr & 7) << 4);  // pre-swizzled byte col
            gload_lds16(K + (size_t)(b * 2048 + t * 64 + rr) * 1024 + h * 64 + (cb >> 1),
                        &KsB[bsel][0] + (size_t)sIdx * 16);
            gload_lds16(Vt + (size_t)(b * 1024 + h * 64 + rr) * 2048 + t * 64 + (cb >> 1),
                        &VsB[bsel][0] + (size_t)sIdx * 16);
        }
    };

    // pack one 32-key group of P (f32x16) into two B-frags (keys lo16 / hi16)
    auto PACK = [&](const f32x16& s, bf16x8& flo, bf16x8& fhi) {
        union { unsigned u[4]; bf16x8 v; } t0, t1;
        {
            unsigned xA = cvtpk_bf16(s[0], s[1]);
            unsigned yC = cvtpk_bf16(s[4], s[5]);
            plane32_swap(xA, yC);
            unsigned xB = cvtpk_bf16(s[2], s[3]);
            unsigned yD = cvtpk_bf16(s[6], s[7]);
            plane32_swap(xB, yD);
            t0.u[0] = xA; t0.u[1] = xB; t0.u[2] = yC; t0.u[3] = yD;
        }
        {
            unsigned xA = cvtpk_bf16(s[8],  s[9]);
            unsigned yC = cvtpk_bf16(s[12], s[13]);
            plane32_swap(xA, yC);
            unsigned xB = cvtpk_bf16(s[10], s[11]);
            unsigned yD = cvtpk_bf16(s[14], s[15]);
            plane32_swap(xB, yD);
            t1.u[0] = xA; t1.u[1] = xB; t1.u[2] = yC; t1.u[3] = yD;
        }
        flo = t0.v; fhi = t1.v;
    };

    STAGE(0, 0);
    for (int t = 0; t < nt; t++) {
        const int cur = t & 1;
        if (t + 1 < nt) {
            STAGE(t + 1, cur ^ 1);
            asm volatile("s_waitcnt vmcnt(4)" ::: "memory");  // tile t landed
        } else {
            asm volatile("s_waitcnt vmcnt(0)" ::: "memory");
        }
        __builtin_amdgcn_s_barrier();
        __builtin_amdgcn_sched_barrier(0);

        const int kv0 = t * 64;
        if (kv0 <= qwave + 31) {            // wave has unmasked work
            const unsigned char* Kb = &KsB[cur][0];
            const unsigned char* Vb = &VsB[cur][0];

            // ---- S^T = K · Q^T : two 32-key groups ----
            f32x16 s0, s1;
#pragma unroll
            for (int i = 0; i < 16; i++) { s0[i] = 0.f; s1[i] = 0.f; }
#pragma unroll
            for (int ks = 0; ks < 4; ks++) {
                bf16x8 a0 = *(const bf16x8*)(Kb + l31 * 128        + ((ks * 32 + hib) ^ swz));
                bf16x8 a1 = *(const bf16x8*)(Kb + (32 + l31) * 128 + ((ks * 32 + hib) ^ swz));
                s0 = mfma32(a0, qf[ks], s0);
                s1 = mfma32(a1, qf[ks], s1);
            }

            // ---- causal mask (raw domain) ----
            if (kv0 + 63 > qwave) {
#pragma unroll
                for (int i = 0; i < 16; i++) {
                    int key = kv0 + (i & 3) + 8 * (i >> 2) + hi4;
                    if (key > qrow)      s0[i] = -3e8f;
                    if (key + 32 > qrow) s1[i] = -3e8f;
                }
            }

            // ---- row max (register tree + one cross-half shfl) ----
            float t16[16];
#pragma unroll
            for (int i = 0; i < 16; i++) t16[i] = fmaxf(s0[i], s1[i]);
#pragma unroll
            for (int i = 0; i < 8; i++) t16[i] = fmaxf(t16[i], t16[i + 8]);
#pragma unroll
            for (int i = 0; i < 4; i++) t16[i] = fmaxf(t16[i], t16[i + 4]);
            float pm = fmaxf(fmaxf(t16[0], t16[1]), fmaxf(t16[2], t16[3]));
            pm = fmaxf(pm, __shfl_xor(pm, 32));

            // ---- defer-max rescale (T13, raw threshold 64 = 8 nats) ----
            if (__any(pm > m + 64.0f)) {
                float mn  = fmaxf(m, pm);
                float fac = exp2_fast((m - mn) * SCL);
                m = mn; l *= fac;
#pragma unroll
                for (int i = 0; i < 16; i++) { O0[i] *= fac; O1[i] *= fac; }
            }

            // ---- P = exp2(s*SCL - m*SCL) ----
            const float nmS = -m * SCL;
#pragma unroll
            for (int i = 0; i < 16; i++) {
                s0[i] = exp2_fast(fmaf(s0[i], SCL, nmS));
                s1[i] = exp2_fast(fmaf(s1[i], SCL, nmS));
            }
            // row sum
#pragma unroll
            for (int i = 0; i < 16; i++) t16[i] = s0[i] + s1[i];
#pragma unroll
            for (int i = 0; i < 8; i++) t16[i] += t16[i + 8];
#pragma unroll
            for (int i = 0; i < 4; i++) t16[i] += t16[i + 4];
            float sm = (t16[0] + t16[1]) + (t16[2] + t16[3]);
            sm += __shfl_xor(sm, 32);
            l += sm;

            // ---- pack P -> 4 B-frags (key slices 0..3) ----
            bf16x8 pA0, pA1, pB0, pB1;
            PACK(s0, pA0, pA1);
            PACK(s1, pB0, pB1);

            // ---- O^T += V^T · P^T ----
#pragma unroll
            for (int half = 0; half < 2; half++) {
                const unsigned char* vrow = Vb + (half * 32 + l31) * 128;
                bf16x8 v0 = *(const bf16x8*)(vrow + ((0  + hib) ^ swz));
                bf16x8 v1 = *(const bf16x8*)(vrow + ((32 + hib) ^ swz));
                bf16x8 v2 = *(const bf16x8*)(vrow + ((64 + hib) ^ swz));
                bf16x8 v3 = *(const bf16x8*)(vrow + ((96 + hib) ^ swz));
                if (half == 0) {
                    O0 = mfma32(v0, pA0, O0); O0 = mfma32(v1, pA1, O0);
                    O0 = mfma32(v2, pB0, O0); O0 = mfma32(v3, pB1, O0);
                } else {
                    O1 = mfma32(v0, pA0, O1); O1 = mfma32(v1, pA1, O1);
                    O1 = mfma32(v2, pB0, O1); O1 = mfma32(v3, pB1, O1);
                }
            }
        }
        asm volatile("s_waitcnt lgkmcnt(0)" ::: "memory");
        __builtin_amdgcn_s_barrier();
    }

    // ---- normalize, write ctx[b*2048+qrow][h*64 + d] ----
    const float rl = 1.0f / l;
    unsigned short* cp = ctx + (size_t)(b * 2048 + qrow) * 1024 + h * 64;
#pragma unroll
    for (int grp = 0; grp < 4; grp++) {
        u16x4 o0 = { f2bf(O0[grp * 4 + 0] * rl), f2bf(O0[grp * 4 + 1] * rl),
                     f2bf(O0[grp * 4 + 2] * rl), f2bf(O0[grp * 4 + 3] * rl) };
        u16x4 o1 = { f2bf(O1[grp * 4 + 0] * rl), f2bf(O1[grp * 4 + 1] * rl),
                     f2bf(O1[grp * 4 + 2] * rl), f2bf(O1[grp * 4 + 3] * rl) };
        *(u16x4*)(cp + grp * 8 + hi4)      = o0;   // d = grp*8 + hi4 + 0..3
        *(u16x4*)(cp + 32 + grp * 8 + hi4) = o1;   // d = 32 + ...
    }
}

// ---------------------------------------------------------------------------
extern "C" void kernel_launch(void* const* d_in, const int* in_sizes, int n_in,
                              void* d_out, int out_size, void* d_ws, size_t ws_size,
                              hipStream_t stream)
{
    const float* q  = (const float*)d_in[0];
    const float* k  = (const float*)d_in[1];
    const float* v  = (const float*)d_in[2];
    // d_in[3] = causal mask (tril) — handled analytically
    const float* Wq = (const float*)d_in[4];
    const float* bq = (const float*)d_in[5];
    const float* Wk = (const float*)d_in[6];
    const float* bk = (const float*)d_in[7];
    const float* Wv = (const float*)d_in[8];
    const float* bv = (const float*)d_in[9];
    const float* Wo = (const float*)d_in[10];
    const float* bo = (const float*)d_in[11];

    const size_t M1 = (size_t)1 << 20;
    unsigned short* ws   = (unsigned short*)d_ws;
    unsigned short* wo_b = ws + 3 * M1;
    unsigned short* vb16 = ws + 20 * M1;       // bf16 v input
    unsigned short* Qw   = ws + 28 * M1;       // [8192,1024] bf16
    unsigned short* Kw   = ws + 36 * M1;       // [8192,1024] bf16

    const bool big = ws_size >= (size_t)52 * M1 * 2;   // 104 MiB available?
    unsigned short* Vt = big ? (ws + 44 * M1)          // non-aliasing: full 3-way fuse
                             : (ws + 4 * M1);          // fallback: alias q-bf16 (dead)
    unsigned short* Cx = big ? (ws + 4 * M1)           // attn out (aliases dead q-bf16)
                             : (ws + 12 * M1);         //          (aliases dead k-bf16)

    cvt_all<<<14336, 256, 0, stream>>>(q, k, v, Wq, Wk, Wv, Wo, ws);

    if (big) {
        gemm_qkv<<<dim3(64, 8, 3), 256, 0, stream>>>(ws, bq, bk, bv, Qw, Kw, Vt);
    } else {
        gemm_qkv<<<dim3(64, 8, 2), 256, 0, stream>>>(ws, bq, bk, bv, Qw, Kw, Vt);
        gemm128<1><<<dim3(64, 8), 256, 0, stream>>>(vb16, ws + 2 * M1, bv, Vt);
    }

    attn_kernel<<<1024, 256, 0, stream>>>(Qw, Kw, Vt, Cx);

    gemm128<2><<<dim3(64, 8), 256, 0, stream>>>(Cx, wo_b, bo, d_out);
}